// Round 1
// baseline (1529.510 us; speedup 1.0000x reference)
//
#include <hip/hip_runtime.h>
#include <math.h>

#define TPB 256

// One block per image. Full network fused: all intermediates live in LDS.
__global__ __launch_bounds__(TPB) void lenet_off_fused(
    const float* __restrict__ x,
    const float* __restrict__ w1s, const float* __restrict__ b1s,
    const float* __restrict__ w1x, const float* __restrict__ b1x,
    const float* __restrict__ w1y, const float* __restrict__ b1y,
    const float* __restrict__ w2s, const float* __restrict__ b2s,
    const float* __restrict__ w2x, const float* __restrict__ b2x,
    const float* __restrict__ w2y, const float* __restrict__ b2y,
    const float* __restrict__ wf1, const float* __restrict__ bf1,
    const float* __restrict__ wf2, const float* __restrict__ bf2,
    const float* __restrict__ wf3, const float* __restrict__ bf3,
    float* __restrict__ out)
{
    __shared__ float xs[676];     // 26x26 input image
    __shared__ float w1[450];     // [3 kinds s,x,y][6][25]
    __shared__ float b1[18];      // [3][6]
    __shared__ float w2[7200];    // [3][16][150]
    __shared__ float b2[48];      // [3][16]
    __shared__ float bufA[3456];  // s1 (6x24x24); later s2 (16x10x10) @0, t2 @1600
    __shared__ float bufB[3456];  // sampled+relu layer1 (6x24x24)
    __shared__ float h1[864];     // pooled layer1 (6x12x12)
    __shared__ float h2[400];     // pooled layer2 (16x5x5), flatten order
    __shared__ float f1[120];
    __shared__ float f2[84];
    __shared__ float f3[10];

    const int tid = threadIdx.x;
    const int b   = blockIdx.x;

    // ---- stage input + conv weights into LDS ----
    const float* xp = x + b * 676;
    for (int i = tid; i < 676; i += TPB) xs[i] = xp[i];
    for (int i = tid; i < 150; i += TPB) {
        w1[i]       = w1s[i];
        w1[150 + i] = w1x[i];
        w1[300 + i] = w1y[i];
    }
    if (tid < 6) { b1[tid] = b1s[tid]; b1[6 + tid] = b1x[tid]; b1[12 + tid] = b1y[tid]; }
    for (int i = tid; i < 2400; i += TPB) {
        w2[i]        = w2s[i];
        w2[2400 + i] = w2x[i];
        w2[4800 + i] = w2y[i];
    }
    if (tid < 16) { b2[tid] = b2s[tid]; b2[16 + tid] = b2x[tid]; b2[32 + tid] = b2y[tid]; }
    __syncthreads();

    // ---- layer1 score conv: 1->6, 5x5, pad 1, out 24x24 ----
    for (int idx = tid; idx < 3456; idx += TPB) {
        int c = idx / 576;
        int p = idx % 576;
        int oy = p / 24, ox = p % 24;
        const float* wc = &w1[c * 25];
        float acc = b1[c];
        #pragma unroll
        for (int ky = 0; ky < 5; ++ky) {
            int iy = oy - 1 + ky;
            if ((unsigned)iy >= 26u) continue;
            #pragma unroll
            for (int kx = 0; kx < 5; ++kx) {
                int ix = ox - 1 + kx;
                if ((unsigned)ix >= 26u) continue;
                acc = fmaf(xs[iy * 26 + ix], wc[ky * 5 + kx], acc);
            }
        }
        bufA[idx] = acc;
    }
    __syncthreads();

    // ---- layer1 offset convs + bilinear sample (zeros) + relu ----
    for (int idx = tid; idx < 3456; idx += TPB) {
        int c = idx / 576;
        int p = idx % 576;
        int oy = p / 24, ox = p % 24;
        const float* wxp = &w1[150 + c * 25];
        const float* wyp = &w1[300 + c * 25];
        float gx = b1[6 + c], gy = b1[12 + c];
        #pragma unroll
        for (int ky = 0; ky < 5; ++ky) {
            int iy = oy - 1 + ky;
            if ((unsigned)iy >= 26u) continue;
            #pragma unroll
            for (int kx = 0; kx < 5; ++kx) {
                int ix = ox - 1 + kx;
                if ((unsigned)ix >= 26u) continue;
                float xv = xs[iy * 26 + ix];
                gx = fmaf(xv, wxp[ky * 5 + kx], gx);
                gy = fmaf(xv, wyp[ky * 5 + kx], gy);
            }
        }
        // grid sample, H=W=24, align_corners=False, zeros padding
        float ixf = (gx + 1.0f) * 12.0f - 0.5f;
        float iyf = (gy + 1.0f) * 12.0f - 0.5f;
        float x0 = floorf(ixf), y0 = floorf(iyf);
        float wx1 = ixf - x0, wy1 = iyf - y0;
        float wx0 = 1.0f - wx1, wy0 = 1.0f - wy1;
        float x1 = x0 + 1.0f, y1 = y0 + 1.0f;
        int xi0 = (int)fminf(fmaxf(x0, 0.0f), 23.0f);
        int yi0 = (int)fminf(fmaxf(y0, 0.0f), 23.0f);
        int xi1 = (int)fminf(fmaxf(x1, 0.0f), 23.0f);
        int yi1 = (int)fminf(fmaxf(y1, 0.0f), 23.0f);
        bool vx0 = (x0 >= 0.0f) && (x0 < 24.0f);
        bool vx1 = (x1 >= 0.0f) && (x1 < 24.0f);
        bool vy0 = (y0 >= 0.0f) && (y0 < 24.0f);
        bool vy1 = (y1 >= 0.0f) && (y1 < 24.0f);
        const float* sc = &bufA[c * 576];
        float v00 = (vy0 && vx0) ? sc[yi0 * 24 + xi0] : 0.0f;
        float v01 = (vy0 && vx1) ? sc[yi0 * 24 + xi1] : 0.0f;
        float v10 = (vy1 && vx0) ? sc[yi1 * 24 + xi0] : 0.0f;
        float v11 = (vy1 && vx1) ? sc[yi1 * 24 + xi1] : 0.0f;
        float val = v00 * wy0 * wx0 + v01 * wy0 * wx1 + v10 * wy1 * wx0 + v11 * wy1 * wx1;
        bufB[idx] = fmaxf(val, 0.0f);
    }
    __syncthreads();

    // ---- maxpool 2x2 -> h1 (6x12x12) ----
    for (int idx = tid; idx < 864; idx += TPB) {
        int c = idx / 144, p = idx % 144;
        int py = p / 12, px = p % 12;
        const float* t = &bufB[c * 576 + py * 48 + px * 2];
        h1[idx] = fmaxf(fmaxf(t[0], t[1]), fmaxf(t[24], t[25]));
    }
    __syncthreads();

    // ---- layer2 score conv: 6->16, 5x5, pad 1, out 10x10 -> bufA[0:1600] ----
    for (int idx = tid; idx < 1600; idx += TPB) {
        int c = idx / 100, p = idx % 100;
        int oy = p / 10, ox = p % 10;
        const float* wc = &w2[c * 150];
        float acc = b2[c];
        for (int i = 0; i < 6; ++i) {
            const float* hi = &h1[i * 144];
            const float* wi = &wc[i * 25];
            #pragma unroll
            for (int ky = 0; ky < 5; ++ky) {
                int iy = oy - 1 + ky;
                if ((unsigned)iy >= 12u) continue;
                #pragma unroll
                for (int kx = 0; kx < 5; ++kx) {
                    int ix = ox - 1 + kx;
                    if ((unsigned)ix >= 12u) continue;
                    acc = fmaf(hi[iy * 12 + ix], wi[ky * 5 + kx], acc);
                }
            }
        }
        bufA[idx] = acc;
    }
    __syncthreads();

    // ---- layer2 offset convs + sample (H=W=10) + relu -> bufA[1600:3200] ----
    for (int idx = tid; idx < 1600; idx += TPB) {
        int c = idx / 100, p = idx % 100;
        int oy = p / 10, ox = p % 10;
        const float* wxp = &w2[2400 + c * 150];
        const float* wyp = &w2[4800 + c * 150];
        float gx = b2[16 + c], gy = b2[32 + c];
        for (int i = 0; i < 6; ++i) {
            const float* hi = &h1[i * 144];
            #pragma unroll
            for (int ky = 0; ky < 5; ++ky) {
                int iy = oy - 1 + ky;
                if ((unsigned)iy >= 12u) continue;
                #pragma unroll
                for (int kx = 0; kx < 5; ++kx) {
                    int ix = ox - 1 + kx;
                    if ((unsigned)ix >= 12u) continue;
                    float hv = hi[iy * 12 + ix];
                    gx = fmaf(hv, wxp[i * 25 + ky * 5 + kx], gx);
                    gy = fmaf(hv, wyp[i * 25 + ky * 5 + kx], gy);
                }
            }
        }
        float ixf = (gx + 1.0f) * 5.0f - 0.5f;
        float iyf = (gy + 1.0f) * 5.0f - 0.5f;
        float x0 = floorf(ixf), y0 = floorf(iyf);
        float wx1 = ixf - x0, wy1 = iyf - y0;
        float wx0 = 1.0f - wx1, wy0 = 1.0f - wy1;
        float x1 = x0 + 1.0f, y1 = y0 + 1.0f;
        int xi0 = (int)fminf(fmaxf(x0, 0.0f), 9.0f);
        int yi0 = (int)fminf(fmaxf(y0, 0.0f), 9.0f);
        int xi1 = (int)fminf(fmaxf(x1, 0.0f), 9.0f);
        int yi1 = (int)fminf(fmaxf(y1, 0.0f), 9.0f);
        bool vx0 = (x0 >= 0.0f) && (x0 < 10.0f);
        bool vx1 = (x1 >= 0.0f) && (x1 < 10.0f);
        bool vy0 = (y0 >= 0.0f) && (y0 < 10.0f);
        bool vy1 = (y1 >= 0.0f) && (y1 < 10.0f);
        const float* sc = &bufA[c * 100];
        float v00 = (vy0 && vx0) ? sc[yi0 * 10 + xi0] : 0.0f;
        float v01 = (vy0 && vx1) ? sc[yi0 * 10 + xi1] : 0.0f;
        float v10 = (vy1 && vx0) ? sc[yi1 * 10 + xi0] : 0.0f;
        float v11 = (vy1 && vx1) ? sc[yi1 * 10 + xi1] : 0.0f;
        float val = v00 * wy0 * wx0 + v01 * wy0 * wx1 + v10 * wy1 * wx0 + v11 * wy1 * wx1;
        bufA[1600 + idx] = fmaxf(val, 0.0f);
    }
    __syncthreads();

    // ---- maxpool 2x2 -> h2 (16x5x5), flatten order c*25+py*5+px ----
    for (int idx = tid; idx < 400; idx += TPB) {
        int c = idx / 25, p = idx % 25;
        int py = p / 5, px = p % 5;
        const float* t = &bufA[1600 + c * 100 + py * 20 + px * 2];
        h2[idx] = fmaxf(fmaxf(t[0], t[1]), fmaxf(t[10], t[11]));
    }
    __syncthreads();

    // ---- FC1: 400 -> 120, relu (2 threads per output) ----
    if (tid < 240) {
        int o = tid >> 1, h = tid & 1;
        const float* wrow = wf1 + o * 400 + h * 200;
        const float* hh = &h2[h * 200];
        float acc = 0.0f;
        for (int k = 0; k < 200; ++k) acc = fmaf(wrow[k], hh[k], acc);
        acc += __shfl_xor(acc, 1);
        if (h == 0) f1[o] = fmaxf(acc + bf1[o], 0.0f);
    }
    __syncthreads();

    // ---- FC2: 120 -> 84, relu ----
    if (tid < 84) {
        const float* wrow = wf2 + tid * 120;
        float acc = bf2[tid];
        for (int k = 0; k < 120; ++k) acc = fmaf(wrow[k], f1[k], acc);
        f2[tid] = fmaxf(acc, 0.0f);
    }
    __syncthreads();

    // ---- FC3: 84 -> 10 ----
    if (tid < 10) {
        const float* wrow = wf3 + tid * 84;
        float acc = bf3[tid];
        for (int k = 0; k < 84; ++k) acc = fmaf(wrow[k], f2[k], acc);
        f3[tid] = acc;
    }
    __syncthreads();

    // ---- softmax over 10, write output ----
    if (tid < 10) {
        float m = f3[0];
        #pragma unroll
        for (int j = 1; j < 10; ++j) m = fmaxf(m, f3[j]);
        float s = 0.0f;
        #pragma unroll
        for (int j = 0; j < 10; ++j) s += expf(f3[j] - m);
        out[b * 10 + tid] = expf(f3[tid] - m) / s;
    }
}

extern "C" void kernel_launch(void* const* d_in, const int* in_sizes, int n_in,
                              void* d_out, int out_size, void* d_ws, size_t ws_size,
                              hipStream_t stream) {
    const float* x   = (const float*)d_in[0];
    const float* w1s = (const float*)d_in[1];
    const float* b1s = (const float*)d_in[2];
    const float* w1x = (const float*)d_in[3];
    const float* b1x = (const float*)d_in[4];
    const float* w1y = (const float*)d_in[5];
    const float* b1y = (const float*)d_in[6];
    const float* w2s = (const float*)d_in[7];
    const float* b2s = (const float*)d_in[8];
    const float* w2x = (const float*)d_in[9];
    const float* b2x = (const float*)d_in[10];
    const float* w2y = (const float*)d_in[11];
    const float* b2y = (const float*)d_in[12];
    const float* wf1 = (const float*)d_in[13];
    const float* bf1 = (const float*)d_in[14];
    const float* wf2 = (const float*)d_in[15];
    const float* bf2 = (const float*)d_in[16];
    const float* wf3 = (const float*)d_in[17];
    const float* bf3 = (const float*)d_in[18];
    float* out = (float*)d_out;

    lenet_off_fused<<<8192, TPB, 0, stream>>>(
        x, w1s, b1s, w1x, b1x, w1y, b1y,
        w2s, b2s, w2x, b2x, w2y, b2y,
        wf1, bf1, wf2, bf2, wf3, bf3, out);
}

// Round 2
// 525.291 us; speedup vs baseline: 2.9117x; 2.9117x over previous
//
#include <hip/hip_runtime.h>
#include <math.h>

#define TPB 256

__device__ __forceinline__ float bilin_zero(const float* __restrict__ img, int N,
                                            float gx, float gy) {
    float fx = (gx + 1.0f) * (0.5f * (float)N) - 0.5f;
    float fy = (gy + 1.0f) * (0.5f * (float)N) - 0.5f;
    float x0 = floorf(fx), y0 = floorf(fy);
    float wx1 = fx - x0, wy1 = fy - y0;
    float wx0 = 1.0f - wx1, wy0 = 1.0f - wy1;
    float x1 = x0 + 1.0f, y1 = y0 + 1.0f;
    float Nm1 = (float)(N - 1);
    int xi0 = (int)fminf(fmaxf(x0, 0.0f), Nm1);
    int yi0 = (int)fminf(fmaxf(y0, 0.0f), Nm1);
    int xi1 = (int)fminf(fmaxf(x1, 0.0f), Nm1);
    int yi1 = (int)fminf(fmaxf(y1, 0.0f), Nm1);
    bool vx0 = (x0 >= 0.0f) && (x0 < (float)N);
    bool vx1 = (x1 >= 0.0f) && (x1 < (float)N);
    bool vy0 = (y0 >= 0.0f) && (y0 < (float)N);
    bool vy1 = (y1 >= 0.0f) && (y1 < (float)N);
    float v00 = (vy0 && vx0) ? img[yi0 * N + xi0] : 0.0f;
    float v01 = (vy0 && vx1) ? img[yi0 * N + xi1] : 0.0f;
    float v10 = (vy1 && vx0) ? img[yi1 * N + xi0] : 0.0f;
    float v11 = (vy1 && vx1) ? img[yi1 * N + xi1] : 0.0f;
    return v00 * wy0 * wx0 + v01 * wy0 * wx1 + v10 * wy1 * wx0 + v11 * wy1 * wx1;
}

// One block per image; fused s/gx/gy convs, fused sample+relu+pool, padded maps.
__global__ __launch_bounds__(TPB, 2) void lenet_off_fused(
    const float* __restrict__ x,
    const float* __restrict__ w1s, const float* __restrict__ b1s,
    const float* __restrict__ w1x, const float* __restrict__ b1x,
    const float* __restrict__ w1y, const float* __restrict__ b1y,
    const float* __restrict__ w2s, const float* __restrict__ b2s,
    const float* __restrict__ w2x, const float* __restrict__ b2x,
    const float* __restrict__ w2y, const float* __restrict__ b2y,
    const float* __restrict__ wf1, const float* __restrict__ bf1,
    const float* __restrict__ wf2, const float* __restrict__ bf2,
    const float* __restrict__ wf3, const float* __restrict__ bf3,
    float* __restrict__ out)
{
    __shared__ __align__(16) float  xs_p[784];    // padded input 28x28
    __shared__ float4 w1i[150];                   // [6][25] interleaved (s,x,y,0)
    __shared__ float4 b1i[6];
    __shared__ float4 w2i[2400];                  // [16][150] interleaved
    __shared__ float4 b2i[16];
    __shared__ __align__(16) float  smap1[3456];  // score map 1: [6][24][24]
    __shared__ __align__(16) float  h1p[1176];    // padded pooled1: [6][14][14]
    __shared__ __align__(16) float  smap2[1600];  // score map 2: [16][10][10]
    __shared__ __align__(16) float  h2[400];      // pooled2 flat [16][5][5]
    __shared__ __align__(16) float  f1[120];
    __shared__ __align__(16) float  f2[84];
    __shared__ float  f3[10];

    const int tid = threadIdx.x;
    const int b   = blockIdx.x;

    // ================= stage =================
    const float* xp = x + b * 676;
    for (int i = tid; i < 784; i += TPB) {
        int r = i / 28, c = i % 28;
        float v = 0.0f;
        if (r >= 1 && r <= 26 && c >= 1 && c <= 26) v = xp[(r - 1) * 26 + (c - 1)];
        xs_p[i] = v;
    }
    for (int i = tid; i < 150; i += TPB)
        w1i[i] = make_float4(w1s[i], w1x[i], w1y[i], 0.0f);
    if (tid < 6)  b1i[tid] = make_float4(b1s[tid], b1x[tid], b1y[tid], 0.0f);
    for (int i = tid; i < 2400; i += TPB)
        w2i[i] = make_float4(w2s[i], w2x[i], w2y[i], 0.0f);
    if (tid < 16) b2i[tid] = make_float4(b2s[tid], b2x[tid], b2y[tid], 0.0f);
    for (int i = tid; i < 1176; i += TPB) h1p[i] = 0.0f;  // zero padded h1
    __syncthreads();

    // ========== layer 1: fused conv(s,gx,gy) ==========
    // thread <-> pooled output (c,py,px): 6*12*12 = 864
    float gxr[4][2][2], gyr[4][2][2];
    #pragma unroll
    for (int it = 0; it < 4; ++it) {
        int idx = tid + it * TPB;
        if (idx < 864) {
            int c = idx / 144, p = idx % 144;
            int py = p / 12, px = p % 12;
            // 6x6 activation window (padded coords rows 2py..2py+5, cols 2px..2px+5)
            float a[6][6];
            #pragma unroll
            for (int r = 0; r < 6; ++r) {
                const float2* rp = (const float2*)&xs_p[(2 * py + r) * 28 + 2 * px];
                float2 v0 = rp[0], v1 = rp[1], v2 = rp[2];
                a[r][0] = v0.x; a[r][1] = v0.y; a[r][2] = v1.x;
                a[r][3] = v1.y; a[r][4] = v2.x; a[r][5] = v2.y;
            }
            float4 bb = b1i[c];
            float s[2][2], agx[2][2], agy[2][2];
            #pragma unroll
            for (int dy = 0; dy < 2; ++dy)
                #pragma unroll
                for (int dx = 0; dx < 2; ++dx) { s[dy][dx] = bb.x; agx[dy][dx] = bb.y; agy[dy][dx] = bb.z; }
            #pragma unroll
            for (int ky = 0; ky < 5; ++ky)
                #pragma unroll
                for (int kx = 0; kx < 5; ++kx) {
                    float4 w = w1i[c * 25 + ky * 5 + kx];
                    #pragma unroll
                    for (int dy = 0; dy < 2; ++dy)
                        #pragma unroll
                        for (int dx = 0; dx < 2; ++dx) {
                            float v = a[ky + dy][kx + dx];
                            s[dy][dx]   = fmaf(v, w.x, s[dy][dx]);
                            agx[dy][dx] = fmaf(v, w.y, agx[dy][dx]);
                            agy[dy][dx] = fmaf(v, w.z, agy[dy][dx]);
                        }
                }
            float* sm = &smap1[c * 576 + (2 * py) * 24 + 2 * px];
            sm[0] = s[0][0]; sm[1] = s[0][1]; sm[24] = s[1][0]; sm[25] = s[1][1];
            #pragma unroll
            for (int dy = 0; dy < 2; ++dy)
                #pragma unroll
                for (int dx = 0; dx < 2; ++dx) { gxr[it][dy][dx] = agx[dy][dx]; gyr[it][dy][dx] = agy[dy][dx]; }
        }
    }
    __syncthreads();

    // ========== layer 1: sample + relu + pool ==========
    #pragma unroll
    for (int it = 0; it < 4; ++it) {
        int idx = tid + it * TPB;
        if (idx < 864) {
            int c = idx / 144, p = idx % 144;
            int py = p / 12, px = p % 12;
            const float* smc = &smap1[c * 576];
            float mx = 0.0f;  // relu floor folded into max
            #pragma unroll
            for (int dy = 0; dy < 2; ++dy)
                #pragma unroll
                for (int dx = 0; dx < 2; ++dx)
                    mx = fmaxf(mx, bilin_zero(smc, 24, gxr[it][dy][dx], gyr[it][dy][dx]));
            h1p[c * 196 + (py + 1) * 14 + (px + 1)] = mx;
        }
    }
    __syncthreads();

    // ========== layer 2: fused conv(s,gx,gy) ==========
    // thread <-> pooled output (c,py,px): 16*5*5 = 400
    float gxr2[2][2][2], gyr2[2][2][2];
    #pragma unroll
    for (int it = 0; it < 2; ++it) {
        int idx = tid + it * TPB;
        if (idx < 400) {
            int c = idx / 25, p = idx % 25;
            int py = p / 5, px = p % 5;
            float4 bb = b2i[c];
            float s[2][2], agx[2][2], agy[2][2];
            #pragma unroll
            for (int dy = 0; dy < 2; ++dy)
                #pragma unroll
                for (int dx = 0; dx < 2; ++dx) { s[dy][dx] = bb.x; agx[dy][dx] = bb.y; agy[dy][dx] = bb.z; }
            for (int i = 0; i < 6; ++i) {
                float a[6][6];
                #pragma unroll
                for (int r = 0; r < 6; ++r) {
                    const float2* rp = (const float2*)&h1p[i * 196 + (2 * py + r) * 14 + 2 * px];
                    float2 v0 = rp[0], v1 = rp[1], v2 = rp[2];
                    a[r][0] = v0.x; a[r][1] = v0.y; a[r][2] = v1.x;
                    a[r][3] = v1.y; a[r][4] = v2.x; a[r][5] = v2.y;
                }
                const float4* wc = &w2i[c * 150 + i * 25];
                #pragma unroll
                for (int ky = 0; ky < 5; ++ky)
                    #pragma unroll
                    for (int kx = 0; kx < 5; ++kx) {
                        float4 w = wc[ky * 5 + kx];
                        #pragma unroll
                        for (int dy = 0; dy < 2; ++dy)
                            #pragma unroll
                            for (int dx = 0; dx < 2; ++dx) {
                                float v = a[ky + dy][kx + dx];
                                s[dy][dx]   = fmaf(v, w.x, s[dy][dx]);
                                agx[dy][dx] = fmaf(v, w.y, agx[dy][dx]);
                                agy[dy][dx] = fmaf(v, w.z, agy[dy][dx]);
                            }
                    }
            }
            float* sm = &smap2[c * 100 + (2 * py) * 10 + 2 * px];
            sm[0] = s[0][0]; sm[1] = s[0][1]; sm[10] = s[1][0]; sm[11] = s[1][1];
            #pragma unroll
            for (int dy = 0; dy < 2; ++dy)
                #pragma unroll
                for (int dx = 0; dx < 2; ++dx) { gxr2[it][dy][dx] = agx[dy][dx]; gyr2[it][dy][dx] = agy[dy][dx]; }
        }
    }
    __syncthreads();

    // ========== layer 2: sample + relu + pool ==========
    #pragma unroll
    for (int it = 0; it < 2; ++it) {
        int idx = tid + it * TPB;
        if (idx < 400) {
            int c = idx / 25, p = idx % 25;
            int py = p / 5, px = p % 5;
            const float* smc = &smap2[c * 100];
            float mx = 0.0f;
            #pragma unroll
            for (int dy = 0; dy < 2; ++dy)
                #pragma unroll
                for (int dx = 0; dx < 2; ++dx)
                    mx = fmaxf(mx, bilin_zero(smc, 10, gxr2[it][dy][dx], gyr2[it][dy][dx]));
            h2[c * 25 + py * 5 + px] = mx;  // flatten order c*25 + y*5 + x
        }
    }
    __syncthreads();

    // ========== FC1: 400 -> 120, relu (2 threads per output) ==========
    if (tid < 240) {
        int o = tid >> 1, h = tid & 1;
        const float4* wrow = (const float4*)(wf1 + o * 400 + h * 200);
        const float4* hh   = (const float4*)&h2[h * 200];
        float acc = 0.0f;
        for (int k = 0; k < 50; ++k) {
            float4 w = wrow[k];
            float4 v = hh[k];
            acc = fmaf(w.x, v.x, acc);
            acc = fmaf(w.y, v.y, acc);
            acc = fmaf(w.z, v.z, acc);
            acc = fmaf(w.w, v.w, acc);
        }
        acc += __shfl_xor(acc, 1);
        if (h == 0) f1[o] = fmaxf(acc + bf1[o], 0.0f);
    }
    __syncthreads();

    // ========== FC2: 120 -> 84, relu ==========
    if (tid < 84) {
        const float4* wrow = (const float4*)(wf2 + tid * 120);
        const float4* hh   = (const float4*)f1;
        float acc = bf2[tid];
        for (int k = 0; k < 30; ++k) {
            float4 w = wrow[k];
            float4 v = hh[k];
            acc = fmaf(w.x, v.x, acc);
            acc = fmaf(w.y, v.y, acc);
            acc = fmaf(w.z, v.z, acc);
            acc = fmaf(w.w, v.w, acc);
        }
        f2[tid] = fmaxf(acc, 0.0f);
    }
    __syncthreads();

    // ========== FC3: 84 -> 10 ==========
    if (tid < 10) {
        const float4* wrow = (const float4*)(wf3 + tid * 84);
        const float4* hh   = (const float4*)f2;
        float acc = bf3[tid];
        for (int k = 0; k < 21; ++k) {
            float4 w = wrow[k];
            float4 v = hh[k];
            acc = fmaf(w.x, v.x, acc);
            acc = fmaf(w.y, v.y, acc);
            acc = fmaf(w.z, v.z, acc);
            acc = fmaf(w.w, v.w, acc);
        }
        f3[tid] = acc;
    }
    __syncthreads();

    // ========== softmax ==========
    if (tid < 10) {
        float m = f3[0];
        #pragma unroll
        for (int j = 1; j < 10; ++j) m = fmaxf(m, f3[j]);
        float ssum = 0.0f;
        #pragma unroll
        for (int j = 0; j < 10; ++j) ssum += expf(f3[j] - m);
        out[b * 10 + tid] = expf(f3[tid] - m) / ssum;
    }
}

extern "C" void kernel_launch(void* const* d_in, const int* in_sizes, int n_in,
                              void* d_out, int out_size, void* d_ws, size_t ws_size,
                              hipStream_t stream) {
    const float* x   = (const float*)d_in[0];
    const float* w1s = (const float*)d_in[1];
    const float* b1s = (const float*)d_in[2];
    const float* w1x = (const float*)d_in[3];
    const float* b1x = (const float*)d_in[4];
    const float* w1y = (const float*)d_in[5];
    const float* b1y = (const float*)d_in[6];
    const float* w2s = (const float*)d_in[7];
    const float* b2s = (const float*)d_in[8];
    const float* w2x = (const float*)d_in[9];
    const float* b2x = (const float*)d_in[10];
    const float* w2y = (const float*)d_in[11];
    const float* b2y = (const float*)d_in[12];
    const float* wf1 = (const float*)d_in[13];
    const float* bf1 = (const float*)d_in[14];
    const float* wf2 = (const float*)d_in[15];
    const float* bf2 = (const float*)d_in[16];
    const float* wf3 = (const float*)d_in[17];
    const float* bf3 = (const float*)d_in[18];
    float* out = (float*)d_out;

    lenet_off_fused<<<8192, TPB, 0, stream>>>(
        x, w1s, b1s, w1x, b1x, w1y, b1y,
        w2s, b2s, w2x, b2x, w2y, b2y,
        wf1, bf1, wf2, bf2, wf3, bf3, out);
}

// Round 3
// 465.266 us; speedup vs baseline: 3.2874x; 1.1290x over previous
//
#include <hip/hip_runtime.h>
#include <math.h>

#define TPB 256

// ---------------- workspace layout (floats) ----------------
#define OFF_W1I   0          // 150 float4 = 600 f
#define OFF_B1I   600        // 6 float4 = 24 f
#define OFF_W2I   624        // 2400 float4 = 9600 f
#define OFF_B2I   10224      // 16 float4 = 64 f
#define OFF_WF1T  10288      // 400x120 = 48000 f
#define OFF_WF2T  58288      // 120x84 = 10080 f
#define OFF_WF3T  68368      // 84x10 = 840 f
#define OFF_H1    69208      // 8192*864 = 7077888 f
#define OFF_H2    7147096    // 8192*400 = 3276800 f
#define WS_FLOATS 10423896ull
#define REQ_WS_BYTES (WS_FLOATS * 4ull)

__device__ __forceinline__ float bilin_zero(const float* __restrict__ img, int N,
                                            float gx, float gy) {
    float fx = (gx + 1.0f) * (0.5f * (float)N) - 0.5f;
    float fy = (gy + 1.0f) * (0.5f * (float)N) - 0.5f;
    float x0 = floorf(fx), y0 = floorf(fy);
    float wx1 = fx - x0, wy1 = fy - y0;
    float wx0 = 1.0f - wx1, wy0 = 1.0f - wy1;
    float x1 = x0 + 1.0f, y1 = y0 + 1.0f;
    float Nm1 = (float)(N - 1);
    int xi0 = (int)fminf(fmaxf(x0, 0.0f), Nm1);
    int yi0 = (int)fminf(fmaxf(y0, 0.0f), Nm1);
    int xi1 = (int)fminf(fmaxf(x1, 0.0f), Nm1);
    int yi1 = (int)fminf(fmaxf(y1, 0.0f), Nm1);
    bool vx0 = (x0 >= 0.0f) && (x0 < (float)N);
    bool vx1 = (x1 >= 0.0f) && (x1 < (float)N);
    bool vy0 = (y0 >= 0.0f) && (y0 < (float)N);
    bool vy1 = (y1 >= 0.0f) && (y1 < (float)N);
    float v00 = (vy0 && vx0) ? img[yi0 * N + xi0] : 0.0f;
    float v01 = (vy0 && vx1) ? img[yi0 * N + xi1] : 0.0f;
    float v10 = (vy1 && vx0) ? img[yi1 * N + xi0] : 0.0f;
    float v11 = (vy1 && vx1) ? img[yi1 * N + xi1] : 0.0f;
    return v00 * wy0 * wx0 + v01 * wy0 * wx1 + v10 * wy1 * wx0 + v11 * wy1 * wx1;
}

// ================= prep: interleave conv weights, transpose FC weights =================
__global__ __launch_bounds__(TPB) void lenet_prep(
    const float* __restrict__ w1s, const float* __restrict__ w1x, const float* __restrict__ w1y,
    const float* __restrict__ b1s, const float* __restrict__ b1x, const float* __restrict__ b1y,
    const float* __restrict__ w2s, const float* __restrict__ w2x, const float* __restrict__ w2y,
    const float* __restrict__ b2s, const float* __restrict__ b2x, const float* __restrict__ b2y,
    const float* __restrict__ wf1, const float* __restrict__ wf2, const float* __restrict__ wf3,
    float* __restrict__ wsf)
{
    int g = blockIdx.x * TPB + threadIdx.x;
    int stride = gridDim.x * TPB;
    float4* w1i = (float4*)(wsf + OFF_W1I);
    float4* b1i = (float4*)(wsf + OFF_B1I);
    float4* w2i = (float4*)(wsf + OFF_W2I);
    float4* b2i = (float4*)(wsf + OFF_B2I);
    for (int i = g; i < 150; i += stride) w1i[i] = make_float4(w1s[i], w1x[i], w1y[i], 0.0f);
    for (int i = g; i < 6; i += stride)   b1i[i] = make_float4(b1s[i], b1x[i], b1y[i], 0.0f);
    for (int i = g; i < 2400; i += stride) w2i[i] = make_float4(w2s[i], w2x[i], w2y[i], 0.0f);
    for (int i = g; i < 16; i += stride)  b2i[i] = make_float4(b2s[i], b2x[i], b2y[i], 0.0f);
    for (int i = g; i < 48000; i += stride) { int k = i / 120, o = i % 120; wsf[OFF_WF1T + i] = wf1[o * 400 + k]; }
    for (int i = g; i < 10080; i += stride) { int k = i / 84,  o = i % 84;  wsf[OFF_WF2T + i] = wf2[o * 120 + k]; }
    for (int i = g; i < 840;   i += stride) { int k = i / 10,  o = i % 10;  wsf[OFF_WF3T + i] = wf3[o * 84 + k]; }
}

// ================= kernel A: conv1 (s,gx,gy) + sample + relu + pool -> h1 =================
__global__ __launch_bounds__(TPB) void lenetA(
    const float* __restrict__ x, const float* __restrict__ wsf, float* __restrict__ h1)
{
    __shared__ __align__(16) float xs_p[784];   // padded 28x28
    __shared__ float4 w1i[150];
    __shared__ float4 b1i[6];
    __shared__ __align__(16) float smap1[3456]; // [6][24][24]

    const int tid = threadIdx.x, b = blockIdx.x;
    const float* xp = x + b * 676;
    for (int i = tid; i < 784; i += TPB) {
        int r = i / 28, c = i % 28;
        float v = 0.0f;
        if (r >= 1 && r <= 26 && c >= 1 && c <= 26) v = xp[(r - 1) * 26 + (c - 1)];
        xs_p[i] = v;
    }
    {
        const float4* w1g = (const float4*)(wsf + OFF_W1I);
        for (int i = tid; i < 150; i += TPB) w1i[i] = w1g[i];
        if (tid < 6) b1i[tid] = ((const float4*)(wsf + OFF_B1I))[tid];
    }
    __syncthreads();

    float gxr[4][2][2], gyr[4][2][2];
    #pragma unroll
    for (int it = 0; it < 4; ++it) {
        int idx = tid + it * TPB;
        if (idx < 864) {
            int c = idx / 144, p = idx % 144;
            int py = p / 12, px = p % 12;
            float a[6][6];
            #pragma unroll
            for (int r = 0; r < 6; ++r) {
                const float2* rp = (const float2*)&xs_p[(2 * py + r) * 28 + 2 * px];
                float2 v0 = rp[0], v1 = rp[1], v2 = rp[2];
                a[r][0] = v0.x; a[r][1] = v0.y; a[r][2] = v1.x;
                a[r][3] = v1.y; a[r][4] = v2.x; a[r][5] = v2.y;
            }
            float4 bb = b1i[c];
            float s[2][2], agx[2][2], agy[2][2];
            #pragma unroll
            for (int dy = 0; dy < 2; ++dy)
                #pragma unroll
                for (int dx = 0; dx < 2; ++dx) { s[dy][dx] = bb.x; agx[dy][dx] = bb.y; agy[dy][dx] = bb.z; }
            #pragma unroll
            for (int ky = 0; ky < 5; ++ky)
                #pragma unroll
                for (int kx = 0; kx < 5; ++kx) {
                    float4 w = w1i[c * 25 + ky * 5 + kx];
                    #pragma unroll
                    for (int dy = 0; dy < 2; ++dy)
                        #pragma unroll
                        for (int dx = 0; dx < 2; ++dx) {
                            float v = a[ky + dy][kx + dx];
                            s[dy][dx]   = fmaf(v, w.x, s[dy][dx]);
                            agx[dy][dx] = fmaf(v, w.y, agx[dy][dx]);
                            agy[dy][dx] = fmaf(v, w.z, agy[dy][dx]);
                        }
                }
            float* sm = &smap1[c * 576 + (2 * py) * 24 + 2 * px];
            sm[0] = s[0][0]; sm[1] = s[0][1]; sm[24] = s[1][0]; sm[25] = s[1][1];
            #pragma unroll
            for (int dy = 0; dy < 2; ++dy)
                #pragma unroll
                for (int dx = 0; dx < 2; ++dx) { gxr[it][dy][dx] = agx[dy][dx]; gyr[it][dy][dx] = agy[dy][dx]; }
        }
    }
    __syncthreads();

    #pragma unroll
    for (int it = 0; it < 4; ++it) {
        int idx = tid + it * TPB;
        if (idx < 864) {
            int c = idx / 144;
            const float* smc = &smap1[c * 576];
            float mx = 0.0f;
            #pragma unroll
            for (int dy = 0; dy < 2; ++dy)
                #pragma unroll
                for (int dx = 0; dx < 2; ++dx)
                    mx = fmaxf(mx, bilin_zero(smc, 24, gxr[it][dy][dx], gyr[it][dy][dx]));
            h1[b * 864 + idx] = mx;
        }
    }
}

// ================= kernel B: conv2 (s,gx,gy) + sample + relu + pool -> h2 =================
__global__ __launch_bounds__(TPB) void lenetB(
    const float* __restrict__ h1, const float* __restrict__ wsf, float* __restrict__ h2)
{
    __shared__ __align__(16) float h1p[1176];   // padded [6][14][14]
    __shared__ float4 b2i[16];
    __shared__ __align__(16) float smap2[1600]; // [16][10][10]

    const int tid = threadIdx.x, b = blockIdx.x;
    const float* h1b = h1 + b * 864;
    for (int i = tid; i < 1176; i += TPB) {
        int ch = i / 196, p = i % 196;
        int r = p / 14, c = p % 14;
        float v = 0.0f;
        if (r >= 1 && r <= 12 && c >= 1 && c <= 12) v = h1b[ch * 144 + (r - 1) * 12 + (c - 1)];
        h1p[i] = v;
    }
    if (tid < 16) b2i[tid] = ((const float4*)(wsf + OFF_B2I))[tid];
    __syncthreads();

    const float4* w2g = (const float4*)(wsf + OFF_W2I);

    float gxr2[2][2][2], gyr2[2][2][2];
    #pragma unroll
    for (int it = 0; it < 2; ++it) {
        int idx = tid + it * TPB;
        if (idx < 400) {
            int c = idx / 25, p = idx % 25;
            int py = p / 5, px = p % 5;
            float4 bb = b2i[c];
            float s[2][2], agx[2][2], agy[2][2];
            #pragma unroll
            for (int dy = 0; dy < 2; ++dy)
                #pragma unroll
                for (int dx = 0; dx < 2; ++dx) { s[dy][dx] = bb.x; agx[dy][dx] = bb.y; agy[dy][dx] = bb.z; }
            for (int i = 0; i < 6; ++i) {
                float a[6][6];
                #pragma unroll
                for (int r = 0; r < 6; ++r) {
                    const float2* rp = (const float2*)&h1p[i * 196 + (2 * py + r) * 14 + 2 * px];
                    float2 v0 = rp[0], v1 = rp[1], v2 = rp[2];
                    a[r][0] = v0.x; a[r][1] = v0.y; a[r][2] = v1.x;
                    a[r][3] = v1.y; a[r][4] = v2.x; a[r][5] = v2.y;
                }
                const float4* wc = &w2g[c * 150 + i * 25];  // broadcast global (L1/L2)
                #pragma unroll
                for (int ky = 0; ky < 5; ++ky)
                    #pragma unroll
                    for (int kx = 0; kx < 5; ++kx) {
                        float4 w = wc[ky * 5 + kx];
                        #pragma unroll
                        for (int dy = 0; dy < 2; ++dy)
                            #pragma unroll
                            for (int dx = 0; dx < 2; ++dx) {
                                float v = a[ky + dy][kx + dx];
                                s[dy][dx]   = fmaf(v, w.x, s[dy][dx]);
                                agx[dy][dx] = fmaf(v, w.y, agx[dy][dx]);
                                agy[dy][dx] = fmaf(v, w.z, agy[dy][dx]);
                            }
                    }
            }
            float* sm = &smap2[c * 100 + (2 * py) * 10 + 2 * px];
            sm[0] = s[0][0]; sm[1] = s[0][1]; sm[10] = s[1][0]; sm[11] = s[1][1];
            #pragma unroll
            for (int dy = 0; dy < 2; ++dy)
                #pragma unroll
                for (int dx = 0; dx < 2; ++dx) { gxr2[it][dy][dx] = agx[dy][dx]; gyr2[it][dy][dx] = agy[dy][dx]; }
        }
    }
    __syncthreads();

    #pragma unroll
    for (int it = 0; it < 2; ++it) {
        int idx = tid + it * TPB;
        if (idx < 400) {
            int c = idx / 25;
            const float* smc = &smap2[c * 100];
            float mx = 0.0f;
            #pragma unroll
            for (int dy = 0; dy < 2; ++dy)
                #pragma unroll
                for (int dx = 0; dx < 2; ++dx)
                    mx = fmaxf(mx, bilin_zero(smc, 10, gxr2[it][dy][dx], gyr2[it][dy][dx]));
            h2[b * 400 + idx] = mx;
        }
    }
}

// ================= kernel C: FC1+FC2+FC3+softmax. wave handles 4 images =================
__global__ __launch_bounds__(TPB) void lenetC(
    const float* __restrict__ h2, const float* __restrict__ wsf,
    const float* __restrict__ bf1, const float* __restrict__ bf2, const float* __restrict__ bf3,
    float* __restrict__ out)
{
    __shared__ float h2s[4][4][400];
    __shared__ float f1s[4][4][120];
    __shared__ float f2s[4][4][84];
    __shared__ float f3s[4][4][10];

    const int tid = threadIdx.x;
    const int w = tid >> 6, lane = tid & 63;
    const int img0 = blockIdx.x * 16 + w * 4;

    for (int j = 0; j < 4; ++j)
        for (int k = lane; k < 400; k += 64)
            h2s[w][j][k] = h2[(img0 + j) * 400 + k];
    __syncthreads();

    // ---- FC1: 400 -> 120, relu ----
    {
        const float* wf1T = wsf + OFF_WF1T;
        float acc1[4] = {0, 0, 0, 0}, acc2[4] = {0, 0, 0, 0};
        for (int k = 0; k < 400; ++k) {
            float wa = wf1T[k * 120 + lane];
            float wb = (lane < 56) ? wf1T[k * 120 + 64 + lane] : 0.0f;
            #pragma unroll
            for (int j = 0; j < 4; ++j) {
                float hv = h2s[w][j][k];
                acc1[j] = fmaf(hv, wa, acc1[j]);
                acc2[j] = fmaf(hv, wb, acc2[j]);
            }
        }
        float bb1 = bf1[lane];
        float bb2 = (lane < 56) ? bf1[64 + lane] : 0.0f;
        #pragma unroll
        for (int j = 0; j < 4; ++j) {
            f1s[w][j][lane] = fmaxf(acc1[j] + bb1, 0.0f);
            if (lane < 56) f1s[w][j][64 + lane] = fmaxf(acc2[j] + bb2, 0.0f);
        }
    }
    __syncthreads();

    // ---- FC2: 120 -> 84, relu ----
    {
        const float* wf2T = wsf + OFF_WF2T;
        float acc1[4], acc2[4];
        float bb1 = bf2[lane];                       // lane < 64 < 84: valid
        float bb2 = (lane < 20) ? bf2[64 + lane] : 0.0f;
        #pragma unroll
        for (int j = 0; j < 4; ++j) { acc1[j] = bb1; acc2[j] = bb2; }
        for (int k = 0; k < 120; ++k) {
            float wa = wf2T[k * 84 + lane];
            float wb = (lane < 20) ? wf2T[k * 84 + 64 + lane] : 0.0f;
            #pragma unroll
            for (int j = 0; j < 4; ++j) {
                float hv = f1s[w][j][k];
                acc1[j] = fmaf(hv, wa, acc1[j]);
                acc2[j] = fmaf(hv, wb, acc2[j]);
            }
        }
        #pragma unroll
        for (int j = 0; j < 4; ++j) {
            f2s[w][j][lane] = fmaxf(acc1[j], 0.0f);
            if (lane < 20) f2s[w][j][64 + lane] = fmaxf(acc2[j], 0.0f);
        }
    }
    __syncthreads();

    // ---- FC3: 84 -> 10 ----
    if (lane < 10) {
        const float* wf3T = wsf + OFF_WF3T;
        float acc[4];
        float bb = bf3[lane];
        #pragma unroll
        for (int j = 0; j < 4; ++j) acc[j] = bb;
        for (int k = 0; k < 84; ++k) {
            float wv = wf3T[k * 10 + lane];
            #pragma unroll
            for (int j = 0; j < 4; ++j) acc[j] = fmaf(f2s[w][j][k], wv, acc[j]);
        }
        #pragma unroll
        for (int j = 0; j < 4; ++j) f3s[w][j][lane] = acc[j];
    }
    __syncthreads();

    // ---- softmax + store ----
    if (lane < 40) {
        int j = lane / 10, c = lane % 10;
        float m = f3s[w][j][0];
        #pragma unroll
        for (int q = 1; q < 10; ++q) m = fmaxf(m, f3s[w][j][q]);
        float ssum = 0.0f;
        #pragma unroll
        for (int q = 0; q < 10; ++q) ssum += expf(f3s[w][j][q] - m);
        out[(img0 + j) * 10 + c] = expf(f3s[w][j][c] - m) / ssum;
    }
}

// ================= fallback: round-2 fully-fused kernel (used if ws too small) =================
__global__ __launch_bounds__(TPB, 2) void lenet_off_fused(
    const float* __restrict__ x,
    const float* __restrict__ w1s, const float* __restrict__ b1s,
    const float* __restrict__ w1x, const float* __restrict__ b1x,
    const float* __restrict__ w1y, const float* __restrict__ b1y,
    const float* __restrict__ w2s, const float* __restrict__ b2s,
    const float* __restrict__ w2x, const float* __restrict__ b2x,
    const float* __restrict__ w2y, const float* __restrict__ b2y,
    const float* __restrict__ wf1, const float* __restrict__ bf1,
    const float* __restrict__ wf2, const float* __restrict__ bf2,
    const float* __restrict__ wf3, const float* __restrict__ bf3,
    float* __restrict__ out)
{
    __shared__ __align__(16) float  xs_p[784];
    __shared__ float4 w1i[150];
    __shared__ float4 b1i[6];
    __shared__ float4 w2i[2400];
    __shared__ float4 b2i[16];
    __shared__ __align__(16) float  smap1[3456];
    __shared__ __align__(16) float  h1p[1176];
    __shared__ __align__(16) float  smap2[1600];
    __shared__ __align__(16) float  h2[400];
    __shared__ __align__(16) float  f1[120];
    __shared__ __align__(16) float  f2[84];
    __shared__ float  f3[10];

    const int tid = threadIdx.x;
    const int b   = blockIdx.x;

    const float* xp = x + b * 676;
    for (int i = tid; i < 784; i += TPB) {
        int r = i / 28, c = i % 28;
        float v = 0.0f;
        if (r >= 1 && r <= 26 && c >= 1 && c <= 26) v = xp[(r - 1) * 26 + (c - 1)];
        xs_p[i] = v;
    }
    for (int i = tid; i < 150; i += TPB)
        w1i[i] = make_float4(w1s[i], w1x[i], w1y[i], 0.0f);
    if (tid < 6)  b1i[tid] = make_float4(b1s[tid], b1x[tid], b1y[tid], 0.0f);
    for (int i = tid; i < 2400; i += TPB)
        w2i[i] = make_float4(w2s[i], w2x[i], w2y[i], 0.0f);
    if (tid < 16) b2i[tid] = make_float4(b2s[tid], b2x[tid], b2y[tid], 0.0f);
    for (int i = tid; i < 1176; i += TPB) h1p[i] = 0.0f;
    __syncthreads();

    float gxr[4][2][2], gyr[4][2][2];
    #pragma unroll
    for (int it = 0; it < 4; ++it) {
        int idx = tid + it * TPB;
        if (idx < 864) {
            int c = idx / 144, p = idx % 144;
            int py = p / 12, px = p % 12;
            float a[6][6];
            #pragma unroll
            for (int r = 0; r < 6; ++r) {
                const float2* rp = (const float2*)&xs_p[(2 * py + r) * 28 + 2 * px];
                float2 v0 = rp[0], v1 = rp[1], v2 = rp[2];
                a[r][0] = v0.x; a[r][1] = v0.y; a[r][2] = v1.x;
                a[r][3] = v1.y; a[r][4] = v2.x; a[r][5] = v2.y;
            }
            float4 bb = b1i[c];
            float s[2][2], agx[2][2], agy[2][2];
            #pragma unroll
            for (int dy = 0; dy < 2; ++dy)
                #pragma unroll
                for (int dx = 0; dx < 2; ++dx) { s[dy][dx] = bb.x; agx[dy][dx] = bb.y; agy[dy][dx] = bb.z; }
            #pragma unroll
            for (int ky = 0; ky < 5; ++ky)
                #pragma unroll
                for (int kx = 0; kx < 5; ++kx) {
                    float4 w = w1i[c * 25 + ky * 5 + kx];
                    #pragma unroll
                    for (int dy = 0; dy < 2; ++dy)
                        #pragma unroll
                        for (int dx = 0; dx < 2; ++dx) {
                            float v = a[ky + dy][kx + dx];
                            s[dy][dx]   = fmaf(v, w.x, s[dy][dx]);
                            agx[dy][dx] = fmaf(v, w.y, agx[dy][dx]);
                            agy[dy][dx] = fmaf(v, w.z, agy[dy][dx]);
                        }
                }
            float* sm = &smap1[c * 576 + (2 * py) * 24 + 2 * px];
            sm[0] = s[0][0]; sm[1] = s[0][1]; sm[24] = s[1][0]; sm[25] = s[1][1];
            #pragma unroll
            for (int dy = 0; dy < 2; ++dy)
                #pragma unroll
                for (int dx = 0; dx < 2; ++dx) { gxr[it][dy][dx] = agx[dy][dx]; gyr[it][dy][dx] = agy[dy][dx]; }
        }
    }
    __syncthreads();

    #pragma unroll
    for (int it = 0; it < 4; ++it) {
        int idx = tid + it * TPB;
        if (idx < 864) {
            int c = idx / 144, p = idx % 144;
            int py = p / 12, px = p % 12;
            const float* smc = &smap1[c * 576];
            float mx = 0.0f;
            #pragma unroll
            for (int dy = 0; dy < 2; ++dy)
                #pragma unroll
                for (int dx = 0; dx < 2; ++dx)
                    mx = fmaxf(mx, bilin_zero(smc, 24, gxr[it][dy][dx], gyr[it][dy][dx]));
            h1p[c * 196 + (py + 1) * 14 + (px + 1)] = mx;
        }
    }
    __syncthreads();

    float gxr2[2][2][2], gyr2[2][2][2];
    #pragma unroll
    for (int it = 0; it < 2; ++it) {
        int idx = tid + it * TPB;
        if (idx < 400) {
            int c = idx / 25, p = idx % 25;
            int py = p / 5, px = p % 5;
            float4 bb = b2i[c];
            float s[2][2], agx[2][2], agy[2][2];
            #pragma unroll
            for (int dy = 0; dy < 2; ++dy)
                #pragma unroll
                for (int dx = 0; dx < 2; ++dx) { s[dy][dx] = bb.x; agx[dy][dx] = bb.y; agy[dy][dx] = bb.z; }
            for (int i = 0; i < 6; ++i) {
                float a[6][6];
                #pragma unroll
                for (int r = 0; r < 6; ++r) {
                    const float2* rp = (const float2*)&h1p[i * 196 + (2 * py + r) * 14 + 2 * px];
                    float2 v0 = rp[0], v1 = rp[1], v2 = rp[2];
                    a[r][0] = v0.x; a[r][1] = v0.y; a[r][2] = v1.x;
                    a[r][3] = v1.y; a[r][4] = v2.x; a[r][5] = v2.y;
                }
                const float4* wc = &w2i[c * 150 + i * 25];
                #pragma unroll
                for (int ky = 0; ky < 5; ++ky)
                    #pragma unroll
                    for (int kx = 0; kx < 5; ++kx) {
                        float4 w = wc[ky * 5 + kx];
                        #pragma unroll
                        for (int dy = 0; dy < 2; ++dy)
                            #pragma unroll
                            for (int dx = 0; dx < 2; ++dx) {
                                float v = a[ky + dy][kx + dx];
                                s[dy][dx]   = fmaf(v, w.x, s[dy][dx]);
                                agx[dy][dx] = fmaf(v, w.y, agx[dy][dx]);
                                agy[dy][dx] = fmaf(v, w.z, agy[dy][dx]);
                            }
                    }
            }
            float* sm = &smap2[c * 100 + (2 * py) * 10 + 2 * px];
            sm[0] = s[0][0]; sm[1] = s[0][1]; sm[10] = s[1][0]; sm[11] = s[1][1];
            #pragma unroll
            for (int dy = 0; dy < 2; ++dy)
                #pragma unroll
                for (int dx = 0; dx < 2; ++dx) { gxr2[it][dy][dx] = agx[dy][dx]; gyr2[it][dy][dx] = agy[dy][dx]; }
        }
    }
    __syncthreads();

    #pragma unroll
    for (int it = 0; it < 2; ++it) {
        int idx = tid + it * TPB;
        if (idx < 400) {
            int c = idx / 25, p = idx % 25;
            int py = p / 5, px = p % 5;
            const float* smc = &smap2[c * 100];
            float mx = 0.0f;
            #pragma unroll
            for (int dy = 0; dy < 2; ++dy)
                #pragma unroll
                for (int dx = 0; dx < 2; ++dx)
                    mx = fmaxf(mx, bilin_zero(smc, 10, gxr2[it][dy][dx], gyr2[it][dy][dx]));
            h2[c * 25 + py * 5 + px] = mx;
        }
    }
    __syncthreads();

    if (tid < 240) {
        int o = tid >> 1, h = tid & 1;
        const float4* wrow = (const float4*)(wf1 + o * 400 + h * 200);
        const float4* hh   = (const float4*)&h2[h * 200];
        float acc = 0.0f;
        for (int k = 0; k < 50; ++k) {
            float4 w = wrow[k]; float4 v = hh[k];
            acc = fmaf(w.x, v.x, acc); acc = fmaf(w.y, v.y, acc);
            acc = fmaf(w.z, v.z, acc); acc = fmaf(w.w, v.w, acc);
        }
        acc += __shfl_xor(acc, 1);
        if (h == 0) f1[o] = fmaxf(acc + bf1[o], 0.0f);
    }
    __syncthreads();

    if (tid < 84) {
        const float4* wrow = (const float4*)(wf2 + tid * 120);
        const float4* hh   = (const float4*)f1;
        float acc = bf2[tid];
        for (int k = 0; k < 30; ++k) {
            float4 w = wrow[k]; float4 v = hh[k];
            acc = fmaf(w.x, v.x, acc); acc = fmaf(w.y, v.y, acc);
            acc = fmaf(w.z, v.z, acc); acc = fmaf(w.w, v.w, acc);
        }
        f2[tid] = fmaxf(acc, 0.0f);
    }
    __syncthreads();

    if (tid < 10) {
        const float4* wrow = (const float4*)(wf3 + tid * 84);
        const float4* hh   = (const float4*)f2;
        float acc = bf3[tid];
        for (int k = 0; k < 21; ++k) {
            float4 w = wrow[k]; float4 v = hh[k];
            acc = fmaf(w.x, v.x, acc); acc = fmaf(w.y, v.y, acc);
            acc = fmaf(w.z, v.z, acc); acc = fmaf(w.w, v.w, acc);
        }
        f3[tid] = acc;
    }
    __syncthreads();

    if (tid < 10) {
        float m = f3[0];
        #pragma unroll
        for (int j = 1; j < 10; ++j) m = fmaxf(m, f3[j]);
        float ssum = 0.0f;
        #pragma unroll
        for (int j = 0; j < 10; ++j) ssum += expf(f3[j] - m);
        out[b * 10 + tid] = expf(f3[tid] - m) / ssum;
    }
}

extern "C" void kernel_launch(void* const* d_in, const int* in_sizes, int n_in,
                              void* d_out, int out_size, void* d_ws, size_t ws_size,
                              hipStream_t stream) {
    const float* x   = (const float*)d_in[0];
    const float* w1s = (const float*)d_in[1];
    const float* b1s = (const float*)d_in[2];
    const float* w1x = (const float*)d_in[3];
    const float* b1x = (const float*)d_in[4];
    const float* w1y = (const float*)d_in[5];
    const float* b1y = (const float*)d_in[6];
    const float* w2s = (const float*)d_in[7];
    const float* b2s = (const float*)d_in[8];
    const float* w2x = (const float*)d_in[9];
    const float* b2x = (const float*)d_in[10];
    const float* w2y = (const float*)d_in[11];
    const float* b2y = (const float*)d_in[12];
    const float* wf1 = (const float*)d_in[13];
    const float* bf1 = (const float*)d_in[14];
    const float* wf2 = (const float*)d_in[15];
    const float* bf2 = (const float*)d_in[16];
    const float* wf3 = (const float*)d_in[17];
    const float* bf3 = (const float*)d_in[18];
    float* out = (float*)d_out;

    if (ws_size >= REQ_WS_BYTES) {
        float* wsf = (float*)d_ws;
        lenet_prep<<<64, TPB, 0, stream>>>(w1s, w1x, w1y, b1s, b1x, b1y,
                                           w2s, w2x, w2y, b2s, b2x, b2y,
                                           wf1, wf2, wf3, wsf);
        lenetA<<<8192, TPB, 0, stream>>>(x, wsf, wsf + OFF_H1);
        lenetB<<<8192, TPB, 0, stream>>>(wsf + OFF_H1, wsf, wsf + OFF_H2);
        lenetC<<<512, TPB, 0, stream>>>(wsf + OFF_H2, wsf, bf1, bf2, bf3, out);
    } else {
        lenet_off_fused<<<8192, TPB, 0, stream>>>(
            x, w1s, b1s, w1x, b1x, w1y, b1y,
            w2s, b2s, w2x, b2x, w2y, b2y,
            wf1, bf1, wf2, bf2, wf3, bf3, out);
    }
}

// Round 4
// 397.267 us; speedup vs baseline: 3.8501x; 1.1712x over previous
//
#include <hip/hip_runtime.h>
#include <math.h>

#define TPB 256

typedef float v2f __attribute__((ext_vector_type(2)));
struct alignas(16) W4 { v2f a; v2f b; };

// acc(lo,hi) += broadcast(ap.lo) * w(lo,hi)
__device__ __forceinline__ void pk_lo(v2f& acc, v2f ap, v2f w) {
    asm("v_pk_fma_f32 %0, %1, %2, %0 op_sel:[0,0,0] op_sel_hi:[0,1,1]"
        : "+v"(acc) : "v"(ap), "v"(w));
}
// acc(lo,hi) += broadcast(ap.hi) * w(lo,hi)
__device__ __forceinline__ void pk_hi(v2f& acc, v2f ap, v2f w) {
    asm("v_pk_fma_f32 %0, %1, %2, %0 op_sel:[1,0,0] op_sel_hi:[1,1,1]"
        : "+v"(acc) : "v"(ap), "v"(w));
}

// ---------------- workspace layout (floats) ----------------
#define OFF_WA_SX 0          // 3*25 W4 = 300 f
#define OFF_WA_YY 300        // 3*25 v2f = 150 f
#define OFF_WB_SX 464        // 8*6*25 W4 = 4800 f  (464*4 B % 16 == 0)
#define OFF_WB_YY 5264       // 8*6*25 v2f = 2400 f
#define OFF_WF1T  7664       // 400x120 = 48000 f
#define OFF_WF2T  55664      // 120x84 = 10080 f
#define OFF_WF3T  65744      // 84x10 = 840 f
#define OFF_H1    66592      // 8192*864 = 7077888 f
#define OFF_H2    7144480    // 8192*400 = 3276800 f
#define WS_FLOATS 10421280ull
#define REQ_WS_BYTES (WS_FLOATS * 4ull)

__device__ __forceinline__ float bilin_zero(const float* __restrict__ img, int N,
                                            float gx, float gy) {
    float fx = (gx + 1.0f) * (0.5f * (float)N) - 0.5f;
    float fy = (gy + 1.0f) * (0.5f * (float)N) - 0.5f;
    float x0 = floorf(fx), y0 = floorf(fy);
    float wx1 = fx - x0, wy1 = fy - y0;
    float wx0 = 1.0f - wx1, wy0 = 1.0f - wy1;
    float x1 = x0 + 1.0f, y1 = y0 + 1.0f;
    float Nm1 = (float)(N - 1);
    int xi0 = (int)fminf(fmaxf(x0, 0.0f), Nm1);
    int yi0 = (int)fminf(fmaxf(y0, 0.0f), Nm1);
    int xi1 = (int)fminf(fmaxf(x1, 0.0f), Nm1);
    int yi1 = (int)fminf(fmaxf(y1, 0.0f), Nm1);
    bool vx0 = (x0 >= 0.0f) && (x0 < (float)N);
    bool vx1 = (x1 >= 0.0f) && (x1 < (float)N);
    bool vy0 = (y0 >= 0.0f) && (y0 < (float)N);
    bool vy1 = (y1 >= 0.0f) && (y1 < (float)N);
    float v00 = (vy0 && vx0) ? img[yi0 * N + xi0] : 0.0f;
    float v01 = (vy0 && vx1) ? img[yi0 * N + xi1] : 0.0f;
    float v10 = (vy1 && vx0) ? img[yi1 * N + xi0] : 0.0f;
    float v11 = (vy1 && vx1) ? img[yi1 * N + xi1] : 0.0f;
    return v00 * wy0 * wx0 + v01 * wy0 * wx1 + v10 * wy1 * wx0 + v11 * wy1 * wx1;
}

// ================= prep: pack conv weight pairs, transpose FC weights =================
__global__ __launch_bounds__(TPB) void lenet_prep(
    const float* __restrict__ w1s, const float* __restrict__ w1x, const float* __restrict__ w1y,
    const float* __restrict__ w2s, const float* __restrict__ w2x, const float* __restrict__ w2y,
    const float* __restrict__ wf1, const float* __restrict__ wf2, const float* __restrict__ wf3,
    float* __restrict__ wsf)
{
    int g = blockIdx.x * TPB + threadIdx.x;
    int stride = gridDim.x * TPB;
    // layer1: channel pairs (2cp, 2cp+1), cp=0..2
    for (int i = g; i < 75; i += stride) {
        int cp = i / 25, t = i % 25;
        int cA = (2 * cp) * 25 + t, cB = (2 * cp + 1) * 25 + t;
        float* p = wsf + OFF_WA_SX + i * 4;
        p[0] = w1s[cA]; p[1] = w1x[cA]; p[2] = w1s[cB]; p[3] = w1x[cB];
        wsf[OFF_WA_YY + i * 2 + 0] = w1y[cA];
        wsf[OFF_WA_YY + i * 2 + 1] = w1y[cB];
    }
    // layer2: channel pairs (cp, cp+8), cp=0..7; r = i_ch*25+t
    for (int i = g; i < 1200; i += stride) {
        int cp = i / 150, r = i % 150;
        int cA = cp * 150 + r, cB = (cp + 8) * 150 + r;
        float* p = wsf + OFF_WB_SX + i * 4;
        p[0] = w2s[cA]; p[1] = w2x[cA]; p[2] = w2s[cB]; p[3] = w2x[cB];
        wsf[OFF_WB_YY + i * 2 + 0] = w2y[cA];
        wsf[OFF_WB_YY + i * 2 + 1] = w2y[cB];
    }
    for (int i = g; i < 48000; i += stride) { int k = i / 120, o = i % 120; wsf[OFF_WF1T + i] = wf1[o * 400 + k]; }
    for (int i = g; i < 10080; i += stride) { int k = i / 84,  o = i % 84;  wsf[OFF_WF2T + i] = wf2[o * 120 + k]; }
    for (int i = g; i < 840;   i += stride) { int k = i / 10,  o = i % 10;  wsf[OFF_WF3T + i] = wf3[o * 84 + k]; }
}

// ================= kernel A: conv1 + sample + relu + pool -> h1 =================
// thread <-> (channel-pair cp, pooled pos p): 3*144 = 432 work items
__global__ __launch_bounds__(TPB) void lenetA(
    const float* __restrict__ x, const float* __restrict__ wsf,
    const float* __restrict__ b1s, const float* __restrict__ b1x, const float* __restrict__ b1y,
    float* __restrict__ h1)
{
    __shared__ __align__(16) float xs_p[784];   // padded 28x28
    __shared__ __align__(16) float smap1[3456]; // [6][24][24]

    const int tid = threadIdx.x, b = blockIdx.x;
    const float* xp = x + b * 676;
    for (int i = tid; i < 784; i += TPB) {
        int r = i / 28, c = i % 28;
        float v = 0.0f;
        if (r >= 1 && r <= 26 && c >= 1 && c <= 26) v = xp[(r - 1) * 26 + (c - 1)];
        xs_p[i] = v;
    }
    __syncthreads();

    const W4*  wsx = (const W4*) (wsf + OFF_WA_SX);
    const v2f* wyy = (const v2f*)(wsf + OFF_WA_YY);

    float gxa[2][2][2][2], gya[2][2][2][2];  // [it][ch][dy][dx]
    #pragma unroll
    for (int it = 0; it < 2; ++it) {
        int idx = tid + it * TPB;
        if (idx < 432) {
            int cp = idx / 144, p = idx % 144;
            int py = p / 12, px = p % 12;
            v2f aw[6][3];
            #pragma unroll
            for (int r = 0; r < 6; ++r) {
                const v2f* rp = (const v2f*)&xs_p[(2 * py + r) * 28 + 2 * px];
                aw[r][0] = rp[0]; aw[r][1] = rp[1]; aw[r][2] = rp[2];
            }
            int c0 = 2 * cp, c1 = 2 * cp + 1;
            v2f a0[2][2], a1[2][2], ay[2][2];
            {
                v2f i0 = {b1s[c0], b1x[c0]};
                v2f i1 = {b1s[c1], b1x[c1]};
                v2f iy = {b1y[c0], b1y[c1]};
                #pragma unroll
                for (int dy = 0; dy < 2; ++dy)
                    #pragma unroll
                    for (int dx = 0; dx < 2; ++dx) { a0[dy][dx] = i0; a1[dy][dx] = i1; ay[dy][dx] = iy; }
            }
            const W4*  wp  = wsx + cp * 25;
            const v2f* wyp = wyy + cp * 25;
            #pragma unroll
            for (int ky = 0; ky < 5; ++ky)
                #pragma unroll
                for (int kx = 0; kx < 5; ++kx) {
                    W4  w  = wp[ky * 5 + kx];
                    v2f wy = wyp[ky * 5 + kx];
                    #pragma unroll
                    for (int dy = 0; dy < 2; ++dy)
                        #pragma unroll
                        for (int dx = 0; dx < 2; ++dx) {
                            int rr = ky + dy, cc = kx + dx;
                            v2f ap = aw[rr][cc >> 1];
                            if ((cc & 1) == 0) {
                                pk_lo(a0[dy][dx], ap, w.a);
                                pk_lo(a1[dy][dx], ap, w.b);
                                pk_lo(ay[dy][dx], ap, wy);
                            } else {
                                pk_hi(a0[dy][dx], ap, w.a);
                                pk_hi(a1[dy][dx], ap, w.b);
                                pk_hi(ay[dy][dx], ap, wy);
                            }
                        }
                }
            float* sm0 = &smap1[c0 * 576 + (2 * py) * 24 + 2 * px];
            float* sm1 = &smap1[c1 * 576 + (2 * py) * 24 + 2 * px];
            sm0[0] = a0[0][0].x; sm0[1] = a0[0][1].x; sm0[24] = a0[1][0].x; sm0[25] = a0[1][1].x;
            sm1[0] = a1[0][0].x; sm1[1] = a1[0][1].x; sm1[24] = a1[1][0].x; sm1[25] = a1[1][1].x;
            #pragma unroll
            for (int dy = 0; dy < 2; ++dy)
                #pragma unroll
                for (int dx = 0; dx < 2; ++dx) {
                    gxa[it][0][dy][dx] = a0[dy][dx].y;  gya[it][0][dy][dx] = ay[dy][dx].x;
                    gxa[it][1][dy][dx] = a1[dy][dx].y;  gya[it][1][dy][dx] = ay[dy][dx].y;
                }
        }
    }
    __syncthreads();

    #pragma unroll
    for (int it = 0; it < 2; ++it) {
        int idx = tid + it * TPB;
        if (idx < 432) {
            int cp = idx / 144, p = idx % 144;
            #pragma unroll
            for (int ch = 0; ch < 2; ++ch) {
                int c = 2 * cp + ch;
                const float* smc = &smap1[c * 576];
                float mx = 0.0f;
                #pragma unroll
                for (int dy = 0; dy < 2; ++dy)
                    #pragma unroll
                    for (int dx = 0; dx < 2; ++dx)
                        mx = fmaxf(mx, bilin_zero(smc, 24, gxa[it][ch][dy][dx], gya[it][ch][dy][dx]));
                h1[b * 864 + c * 144 + p] = mx;
            }
        }
    }
}

// ================= kernel B: conv2 + sample + relu + pool -> h2 =================
// thread <-> (channel-pair cp in {cp,cp+8}, pooled pos p): 8*25 = 200 work items
__global__ __launch_bounds__(TPB) void lenetB(
    const float* __restrict__ h1, const float* __restrict__ wsf,
    const float* __restrict__ b2s, const float* __restrict__ b2x, const float* __restrict__ b2y,
    float* __restrict__ h2)
{
    __shared__ __align__(16) float h1p[1176];   // padded [6][14][14]
    __shared__ __align__(16) float smap2[1600]; // [16][10][10]

    const int tid = threadIdx.x, b = blockIdx.x;
    const float* h1b = h1 + b * 864;
    for (int i = tid; i < 1176; i += TPB) {
        int ch = i / 196, p = i % 196;
        int r = p / 14, c = p % 14;
        float v = 0.0f;
        if (r >= 1 && r <= 12 && c >= 1 && c <= 12) v = h1b[ch * 144 + (r - 1) * 12 + (c - 1)];
        h1p[i] = v;
    }
    __syncthreads();

    const W4*  wsx = (const W4*) (wsf + OFF_WB_SX);
    const v2f* wyy = (const v2f*)(wsf + OFF_WB_YY);

    float gxa[2][2][2], gya[2][2][2];  // [ch][dy][dx]
    if (tid < 200) {
        int cp = tid / 25, p = tid % 25;
        int py = p / 5, px = p % 5;
        int c0 = cp, c1 = cp + 8;
        v2f a0[2][2], a1[2][2], ay[2][2];
        {
            v2f i0 = {b2s[c0], b2x[c0]};
            v2f i1 = {b2s[c1], b2x[c1]};
            v2f iy = {b2y[c0], b2y[c1]};
            #pragma unroll
            for (int dy = 0; dy < 2; ++dy)
                #pragma unroll
                for (int dx = 0; dx < 2; ++dx) { a0[dy][dx] = i0; a1[dy][dx] = i1; ay[dy][dx] = iy; }
        }
        #pragma unroll
        for (int i = 0; i < 6; ++i) {
            v2f aw[6][3];
            #pragma unroll
            for (int r = 0; r < 6; ++r) {
                const v2f* rp = (const v2f*)&h1p[i * 196 + (2 * py + r) * 14 + 2 * px];
                aw[r][0] = rp[0]; aw[r][1] = rp[1]; aw[r][2] = rp[2];
            }
            const W4*  wp  = wsx + (cp * 6 + i) * 25;
            const v2f* wyp = wyy + (cp * 6 + i) * 25;
            #pragma unroll
            for (int ky = 0; ky < 5; ++ky)
                #pragma unroll
                for (int kx = 0; kx < 5; ++kx) {
                    W4  w  = wp[ky * 5 + kx];
                    v2f wy = wyp[ky * 5 + kx];
                    #pragma unroll
                    for (int dy = 0; dy < 2; ++dy)
                        #pragma unroll
                        for (int dx = 0; dx < 2; ++dx) {
                            int rr = ky + dy, cc = kx + dx;
                            v2f ap = aw[rr][cc >> 1];
                            if ((cc & 1) == 0) {
                                pk_lo(a0[dy][dx], ap, w.a);
                                pk_lo(a1[dy][dx], ap, w.b);
                                pk_lo(ay[dy][dx], ap, wy);
                            } else {
                                pk_hi(a0[dy][dx], ap, w.a);
                                pk_hi(a1[dy][dx], ap, w.b);
                                pk_hi(ay[dy][dx], ap, wy);
                            }
                        }
                }
        }
        float* sm0 = &smap2[c0 * 100 + (2 * py) * 10 + 2 * px];
        float* sm1 = &smap2[c1 * 100 + (2 * py) * 10 + 2 * px];
        sm0[0] = a0[0][0].x; sm0[1] = a0[0][1].x; sm0[10] = a0[1][0].x; sm0[11] = a0[1][1].x;
        sm1[0] = a1[0][0].x; sm1[1] = a1[0][1].x; sm1[10] = a1[1][0].x; sm1[11] = a1[1][1].x;
        #pragma unroll
        for (int dy = 0; dy < 2; ++dy)
            #pragma unroll
            for (int dx = 0; dx < 2; ++dx) {
                gxa[0][dy][dx] = a0[dy][dx].y;  gya[0][dy][dx] = ay[dy][dx].x;
                gxa[1][dy][dx] = a1[dy][dx].y;  gya[1][dy][dx] = ay[dy][dx].y;
            }
    }
    __syncthreads();

    if (tid < 200) {
        int cp = tid / 25, p = tid % 25;
        #pragma unroll
        for (int ch = 0; ch < 2; ++ch) {
            int c = cp + ch * 8;
            const float* smc = &smap2[c * 100];
            float mx = 0.0f;
            #pragma unroll
            for (int dy = 0; dy < 2; ++dy)
                #pragma unroll
                for (int dx = 0; dx < 2; ++dx)
                    mx = fmaxf(mx, bilin_zero(smc, 10, gxa[ch][dy][dx], gya[ch][dy][dx]));
            h2[b * 400 + c * 25 + p] = mx;
        }
    }
}

// ================= kernel C: FC1+FC2+FC3+softmax. wave handles 4 images =================
__global__ __launch_bounds__(TPB) void lenetC(
    const float* __restrict__ h2, const float* __restrict__ wsf,
    const float* __restrict__ bf1, const float* __restrict__ bf2, const float* __restrict__ bf3,
    float* __restrict__ out)
{
    __shared__ float h2s[4][4][400];
    __shared__ float f1s[4][4][120];
    __shared__ float f2s[4][4][84];
    __shared__ float f3s[4][4][10];

    const int tid = threadIdx.x;
    const int w = tid >> 6, lane = tid & 63;
    const int img0 = blockIdx.x * 16 + w * 4;

    for (int j = 0; j < 4; ++j)
        for (int k = lane; k < 400; k += 64)
            h2s[w][j][k] = h2[(img0 + j) * 400 + k];
    __syncthreads();

    {
        const float* wf1T = wsf + OFF_WF1T;
        float acc1[4] = {0, 0, 0, 0}, acc2[4] = {0, 0, 0, 0};
        for (int k = 0; k < 400; ++k) {
            float wa = wf1T[k * 120 + lane];
            float wb = (lane < 56) ? wf1T[k * 120 + 64 + lane] : 0.0f;
            #pragma unroll
            for (int j = 0; j < 4; ++j) {
                float hv = h2s[w][j][k];
                acc1[j] = fmaf(hv, wa, acc1[j]);
                acc2[j] = fmaf(hv, wb, acc2[j]);
            }
        }
        float bb1 = bf1[lane];
        float bb2 = (lane < 56) ? bf1[64 + lane] : 0.0f;
        #pragma unroll
        for (int j = 0; j < 4; ++j) {
            f1s[w][j][lane] = fmaxf(acc1[j] + bb1, 0.0f);
            if (lane < 56) f1s[w][j][64 + lane] = fmaxf(acc2[j] + bb2, 0.0f);
        }
    }
    __syncthreads();

    {
        const float* wf2T = wsf + OFF_WF2T;
        float acc1[4], acc2[4];
        float bb1 = bf2[lane];
        float bb2 = (lane < 20) ? bf2[64 + lane] : 0.0f;
        #pragma unroll
        for (int j = 0; j < 4; ++j) { acc1[j] = bb1; acc2[j] = bb2; }
        for (int k = 0; k < 120; ++k) {
            float wa = wf2T[k * 84 + lane];
            float wb = (lane < 20) ? wf2T[k * 84 + 64 + lane] : 0.0f;
            #pragma unroll
            for (int j = 0; j < 4; ++j) {
                float hv = f1s[w][j][k];
                acc1[j] = fmaf(hv, wa, acc1[j]);
                acc2[j] = fmaf(hv, wb, acc2[j]);
            }
        }
        #pragma unroll
        for (int j = 0; j < 4; ++j) {
            f2s[w][j][lane] = fmaxf(acc1[j], 0.0f);
            if (lane < 20) f2s[w][j][64 + lane] = fmaxf(acc2[j], 0.0f);
        }
    }
    __syncthreads();

    if (lane < 10) {
        const float* wf3T = wsf + OFF_WF3T;
        float acc[4];
        float bb = bf3[lane];
        #pragma unroll
        for (int j = 0; j < 4; ++j) acc[j] = bb;
        for (int k = 0; k < 84; ++k) {
            float wv = wf3T[k * 10 + lane];
            #pragma unroll
            for (int j = 0; j < 4; ++j) acc[j] = fmaf(f2s[w][j][k], wv, acc[j]);
        }
        #pragma unroll
        for (int j = 0; j < 4; ++j) f3s[w][j][lane] = acc[j];
    }
    __syncthreads();

    if (lane < 40) {
        int j = lane / 10, c = lane % 10;
        float m = f3s[w][j][0];
        #pragma unroll
        for (int q = 1; q < 10; ++q) m = fmaxf(m, f3s[w][j][q]);
        float ssum = 0.0f;
        #pragma unroll
        for (int q = 0; q < 10; ++q) ssum += expf(f3s[w][j][q] - m);
        out[(img0 + j) * 10 + c] = expf(f3s[w][j][c] - m) / ssum;
    }
}

// ================= fallback: round-2 fully-fused kernel (used if ws too small) =================
__global__ __launch_bounds__(TPB, 2) void lenet_off_fused(
    const float* __restrict__ x,
    const float* __restrict__ w1s, const float* __restrict__ b1s,
    const float* __restrict__ w1x, const float* __restrict__ b1x,
    const float* __restrict__ w1y, const float* __restrict__ b1y,
    const float* __restrict__ w2s, const float* __restrict__ b2s,
    const float* __restrict__ w2x, const float* __restrict__ b2x,
    const float* __restrict__ w2y, const float* __restrict__ b2y,
    const float* __restrict__ wf1, const float* __restrict__ bf1,
    const float* __restrict__ wf2, const float* __restrict__ bf2,
    const float* __restrict__ wf3, const float* __restrict__ bf3,
    float* __restrict__ out)
{
    __shared__ __align__(16) float  xs_p[784];
    __shared__ float4 w1i[150];
    __shared__ float4 b1i[6];
    __shared__ float4 w2i[2400];
    __shared__ float4 b2i[16];
    __shared__ __align__(16) float  smap1[3456];
    __shared__ __align__(16) float  h1p[1176];
    __shared__ __align__(16) float  smap2[1600];
    __shared__ __align__(16) float  h2[400];
    __shared__ __align__(16) float  f1[120];
    __shared__ __align__(16) float  f2[84];
    __shared__ float  f3[10];

    const int tid = threadIdx.x;
    const int b   = blockIdx.x;

    const float* xp = x + b * 676;
    for (int i = tid; i < 784; i += TPB) {
        int r = i / 28, c = i % 28;
        float v = 0.0f;
        if (r >= 1 && r <= 26 && c >= 1 && c <= 26) v = xp[(r - 1) * 26 + (c - 1)];
        xs_p[i] = v;
    }
    for (int i = tid; i < 150; i += TPB)
        w1i[i] = make_float4(w1s[i], w1x[i], w1y[i], 0.0f);
    if (tid < 6)  b1i[tid] = make_float4(b1s[tid], b1x[tid], b1y[tid], 0.0f);
    for (int i = tid; i < 2400; i += TPB)
        w2i[i] = make_float4(w2s[i], w2x[i], w2y[i], 0.0f);
    if (tid < 16) b2i[tid] = make_float4(b2s[tid], b2x[tid], b2y[tid], 0.0f);
    for (int i = tid; i < 1176; i += TPB) h1p[i] = 0.0f;
    __syncthreads();

    float gxr[4][2][2], gyr[4][2][2];
    #pragma unroll
    for (int it = 0; it < 4; ++it) {
        int idx = tid + it * TPB;
        if (idx < 864) {
            int c = idx / 144, p = idx % 144;
            int py = p / 12, px = p % 12;
            float a[6][6];
            #pragma unroll
            for (int r = 0; r < 6; ++r) {
                const float2* rp = (const float2*)&xs_p[(2 * py + r) * 28 + 2 * px];
                float2 v0 = rp[0], v1 = rp[1], v2 = rp[2];
                a[r][0] = v0.x; a[r][1] = v0.y; a[r][2] = v1.x;
                a[r][3] = v1.y; a[r][4] = v2.x; a[r][5] = v2.y;
            }
            float4 bb = b1i[c];
            float s[2][2], agx[2][2], agy[2][2];
            #pragma unroll
            for (int dy = 0; dy < 2; ++dy)
                #pragma unroll
                for (int dx = 0; dx < 2; ++dx) { s[dy][dx] = bb.x; agx[dy][dx] = bb.y; agy[dy][dx] = bb.z; }
            #pragma unroll
            for (int ky = 0; ky < 5; ++ky)
                #pragma unroll
                for (int kx = 0; kx < 5; ++kx) {
                    float4 w = w1i[c * 25 + ky * 5 + kx];
                    #pragma unroll
                    for (int dy = 0; dy < 2; ++dy)
                        #pragma unroll
                        for (int dx = 0; dx < 2; ++dx) {
                            float v = a[ky + dy][kx + dx];
                            s[dy][dx]   = fmaf(v, w.x, s[dy][dx]);
                            agx[dy][dx] = fmaf(v, w.y, agx[dy][dx]);
                            agy[dy][dx] = fmaf(v, w.z, agy[dy][dx]);
                        }
                }
            float* sm = &smap1[c * 576 + (2 * py) * 24 + 2 * px];
            sm[0] = s[0][0]; sm[1] = s[0][1]; sm[24] = s[1][0]; sm[25] = s[1][1];
            #pragma unroll
            for (int dy = 0; dy < 2; ++dy)
                #pragma unroll
                for (int dx = 0; dx < 2; ++dx) { gxr[it][dy][dx] = agx[dy][dx]; gyr[it][dy][dx] = agy[dy][dx]; }
        }
    }
    __syncthreads();

    #pragma unroll
    for (int it = 0; it < 4; ++it) {
        int idx = tid + it * TPB;
        if (idx < 864) {
            int c = idx / 144, p = idx % 144;
            int py = p / 12, px = p % 12;
            const float* smc = &smap1[c * 576];
            float mx = 0.0f;
            #pragma unroll
            for (int dy = 0; dy < 2; ++dy)
                #pragma unroll
                for (int dx = 0; dx < 2; ++dx)
                    mx = fmaxf(mx, bilin_zero(smc, 24, gxr[it][dy][dx], gyr[it][dy][dx]));
            h1p[c * 196 + (py + 1) * 14 + (px + 1)] = mx;
        }
    }
    __syncthreads();

    float gxr2[2][2][2], gyr2[2][2][2];
    #pragma unroll
    for (int it = 0; it < 2; ++it) {
        int idx = tid + it * TPB;
        if (idx < 400) {
            int c = idx / 25, p = idx % 25;
            int py = p / 5, px = p % 5;
            float4 bb = b2i[c];
            float s[2][2], agx[2][2], agy[2][2];
            #pragma unroll
            for (int dy = 0; dy < 2; ++dy)
                #pragma unroll
                for (int dx = 0; dx < 2; ++dx) { s[dy][dx] = bb.x; agx[dy][dx] = bb.y; agy[dy][dx] = bb.z; }
            for (int i = 0; i < 6; ++i) {
                float a[6][6];
                #pragma unroll
                for (int r = 0; r < 6; ++r) {
                    const float2* rp = (const float2*)&h1p[i * 196 + (2 * py + r) * 14 + 2 * px];
                    float2 v0 = rp[0], v1 = rp[1], v2 = rp[2];
                    a[r][0] = v0.x; a[r][1] = v0.y; a[r][2] = v1.x;
                    a[r][3] = v1.y; a[r][4] = v2.x; a[r][5] = v2.y;
                }
                const float4* wc = &w2i[c * 150 + i * 25];
                #pragma unroll
                for (int ky = 0; ky < 5; ++ky)
                    #pragma unroll
                    for (int kx = 0; kx < 5; ++kx) {
                        float4 w = wc[ky * 5 + kx];
                        #pragma unroll
                        for (int dy = 0; dy < 2; ++dy)
                            #pragma unroll
                            for (int dx = 0; dx < 2; ++dx) {
                                float v = a[ky + dy][kx + dx];
                                s[dy][dx]   = fmaf(v, w.x, s[dy][dx]);
                                agx[dy][dx] = fmaf(v, w.y, agx[dy][dx]);
                                agy[dy][dx] = fmaf(v, w.z, agy[dy][dx]);
                            }
                    }
            }
            float* sm = &smap2[c * 100 + (2 * py) * 10 + 2 * px];
            sm[0] = s[0][0]; sm[1] = s[0][1]; sm[10] = s[1][0]; sm[11] = s[1][1];
            #pragma unroll
            for (int dy = 0; dy < 2; ++dy)
                #pragma unroll
                for (int dx = 0; dx < 2; ++dx) { gxr2[it][dy][dx] = agx[dy][dx]; gyr2[it][dy][dx] = agy[dy][dx]; }
        }
    }
    __syncthreads();

    #pragma unroll
    for (int it = 0; it < 2; ++it) {
        int idx = tid + it * TPB;
        if (idx < 400) {
            int c = idx / 25, p = idx % 25;
            int py = p / 5, px = p % 5;
            const float* smc = &smap2[c * 100];
            float mx = 0.0f;
            #pragma unroll
            for (int dy = 0; dy < 2; ++dy)
                #pragma unroll
                for (int dx = 0; dx < 2; ++dx)
                    mx = fmaxf(mx, bilin_zero(smc, 10, gxr2[it][dy][dx], gyr2[it][dy][dx]));
            h2[c * 25 + py * 5 + px] = mx;
        }
    }
    __syncthreads();

    if (tid < 240) {
        int o = tid >> 1, h = tid & 1;
        const float4* wrow = (const float4*)(wf1 + o * 400 + h * 200);
        const float4* hh   = (const float4*)&h2[h * 200];
        float acc = 0.0f;
        for (int k = 0; k < 50; ++k) {
            float4 w = wrow[k]; float4 v = hh[k];
            acc = fmaf(w.x, v.x, acc); acc = fmaf(w.y, v.y, acc);
            acc = fmaf(w.z, v.z, acc); acc = fmaf(w.w, v.w, acc);
        }
        acc += __shfl_xor(acc, 1);
        if (h == 0) f1[o] = fmaxf(acc + bf1[o], 0.0f);
    }
    __syncthreads();

    if (tid < 84) {
        const float4* wrow = (const float4*)(wf2 + tid * 120);
        const float4* hh   = (const float4*)f1;
        float acc = bf2[tid];
        for (int k = 0; k < 30; ++k) {
            float4 w = wrow[k]; float4 v = hh[k];
            acc = fmaf(w.x, v.x, acc); acc = fmaf(w.y, v.y, acc);
            acc = fmaf(w.z, v.z, acc); acc = fmaf(w.w, v.w, acc);
        }
        f2[tid] = fmaxf(acc, 0.0f);
    }
    __syncthreads();

    if (tid < 10) {
        const float4* wrow = (const float4*)(wf3 + tid * 84);
        const float4* hh   = (const float4*)f2;
        float acc = bf3[tid];
        for (int k = 0; k < 21; ++k) {
            float4 w = wrow[k]; float4 v = hh[k];
            acc = fmaf(w.x, v.x, acc); acc = fmaf(w.y, v.y, acc);
            acc = fmaf(w.z, v.z, acc); acc = fmaf(w.w, v.w, acc);
        }
        f3[tid] = acc;
    }
    __syncthreads();

    if (tid < 10) {
        float m = f3[0];
        #pragma unroll
        for (int j = 1; j < 10; ++j) m = fmaxf(m, f3[j]);
        float ssum = 0.0f;
        #pragma unroll
        for (int j = 0; j < 10; ++j) ssum += expf(f3[j] - m);
        out[b * 10 + tid] = expf(f3[tid] - m) / ssum;
    }
}

extern "C" void kernel_launch(void* const* d_in, const int* in_sizes, int n_in,
                              void* d_out, int out_size, void* d_ws, size_t ws_size,
                              hipStream_t stream) {
    const float* x   = (const float*)d_in[0];
    const float* w1s = (const float*)d_in[1];
    const float* b1s = (const float*)d_in[2];
    const float* w1x = (const float*)d_in[3];
    const float* b1x = (const float*)d_in[4];
    const float* w1y = (const float*)d_in[5];
    const float* b1y = (const float*)d_in[6];
    const float* w2s = (const float*)d_in[7];
    const float* b2s = (const float*)d_in[8];
    const float* w2x = (const float*)d_in[9];
    const float* b2x = (const float*)d_in[10];
    const float* w2y = (const float*)d_in[11];
    const float* b2y = (const float*)d_in[12];
    const float* wf1 = (const float*)d_in[13];
    const float* bf1 = (const float*)d_in[14];
    const float* wf2 = (const float*)d_in[15];
    const float* bf2 = (const float*)d_in[16];
    const float* wf3 = (const float*)d_in[17];
    const float* bf3 = (const float*)d_in[18];
    float* out = (float*)d_out;

    if (ws_size >= REQ_WS_BYTES) {
        float* wsf = (float*)d_ws;
        lenet_prep<<<64, TPB, 0, stream>>>(w1s, w1x, w1y, w2s, w2x, w2y,
                                           wf1, wf2, wf3, wsf);
        lenetA<<<8192, TPB, 0, stream>>>(x, wsf, b1s, b1x, b1y, wsf + OFF_H1);
        lenetB<<<8192, TPB, 0, stream>>>(wsf + OFF_H1, wsf, b2s, b2x, b2y, wsf + OFF_H2);
        lenetC<<<512, TPB, 0, stream>>>(wsf + OFF_H2, wsf, bf1, bf2, bf3, out);
    } else {
        lenet_off_fused<<<8192, TPB, 0, stream>>>(
            x, w1s, b1s, w1x, b1x, w1y, b1y,
            w2s, b2s, w2x, b2x, w2y, b2y,
            wf1, bf1, wf2, bf2, wf3, bf3, out);
    }
}